// Round 1
// baseline (3209.315 us; speedup 1.0000x reference)
//
#include <hip/hip_runtime.h>
#include <math.h>

// kNN (B=1024, C=500000, D=64) + inverse-distance weighting, top-50.
// Pipeline: tnorm -> per-query radius via sampled histogram -> radius filter
// (candidate append) -> per-query 50x argmin extraction + weighted sum.
// Round 1: fp32 vector everywhere (correctness first; MFMA later).

#define DELTA_SMOOTH 1e-3f
#define K_NEIGH 50
#define MAXCAP 4096          // candidate buffer per query (expected ~1500)
#define SAMPLE 4096          // sample rows for threshold histogram
#define SAMPLE_TARGET 12     // sample count at radius -> ~1465 expected full count
#define NBINS 256
#define TSPLIT 512           // table chunks in filter pass

// ---------------- Kernel 1: table row norms ----------------
__global__ __launch_bounds__(256) void tnorm_kernel(
    const float* __restrict__ tk, float* __restrict__ tnorm, int C) {
  // one 64-lane wave per row (D==64), block = 4 rows
  int row = blockIdx.x * 4 + (threadIdx.x >> 6);
  int lane = threadIdx.x & 63;
  if (row >= C) return;
  float v = tk[(size_t)row * 64 + lane];
  float s = v * v;
  #pragma unroll
  for (int off = 32; off > 0; off >>= 1) s += __shfl_down(s, off);
  if (lane == 0) tnorm[row] = s;
}

// ---------------- Kernel 2: per-query threshold from sampled histogram ----------------
__global__ __launch_bounds__(256) void qthresh_kernel(
    const float* __restrict__ keys, const float* __restrict__ tk,
    const float* __restrict__ tnorm, float* __restrict__ thr,
    float* __restrict__ qnorm, int C) {
  int q = blockIdx.x;
  __shared__ __align__(16) float kq[64];
  __shared__ unsigned hist[NBINS];
  __shared__ float qn_sh;
  int tid = threadIdx.x;
  if (tid < 64) kq[tid] = keys[(size_t)q * 64 + tid];
  if (tid < NBINS) hist[tid] = 0u;
  __syncthreads();
  if (tid < 64) {
    float v = kq[tid];
    float s = v * v;
    #pragma unroll
    for (int off = 32; off > 0; off >>= 1) s += __shfl_down(s, off);
    if (tid == 0) qn_sh = s;
  }
  __syncthreads();
  float qn = qn_sh;
  const float4* k4 = (const float4*)kq;
  int S = SAMPLE < C ? SAMPLE : C;
  for (int r = tid; r < S; r += 256) {
    const float4* trow = (const float4*)(tk + (size_t)r * 64);
    float a0 = 0.f, a1 = 0.f, a2 = 0.f, a3 = 0.f;
    #pragma unroll
    for (int j = 0; j < 16; j++) {
      float4 tv = trow[j];
      float4 kv = k4[j];
      a0 += kv.x * tv.x; a1 += kv.y * tv.y; a2 += kv.z * tv.z; a3 += kv.w * tv.w;
    }
    float dot = (a0 + a1) + (a2 + a3);
    float d2 = qn + tnorm[r] - 2.f * dot;
    int b = (int)d2;
    b = b < 0 ? 0 : (b > NBINS - 1 ? NBINS - 1 : b);
    atomicAdd(&hist[b], 1u);
  }
  __syncthreads();
  if (tid == 0) {
    unsigned cum = 0;
    int bstar = NBINS - 1;
    for (int b = 0; b < NBINS; b++) {
      cum += hist[b];
      if (cum >= SAMPLE_TARGET) { bstar = b; break; }
    }
    // filter compares (tn - 2*dot) < thr  <=>  d2_full < bstar+1
    thr[q] = (float)(bstar + 1) - qn;
    qnorm[q] = qn;
  }
}

// ---------------- Kernel 3: radius filter over full table ----------------
__global__ __launch_bounds__(256) void filter_kernel(
    const float* __restrict__ keys, const float* __restrict__ tk,
    const float* __restrict__ tnorm, const float* __restrict__ thr,
    int* __restrict__ cnt, int* __restrict__ candi, float* __restrict__ candd,
    int C, int qtiles, int cap) {
  int qt = blockIdx.x % qtiles;        // query tile (fast-varying)
  int ts = blockIdx.x / qtiles;        // table chunk
  int q = qt * 256 + threadIdx.x;
  int chunk = (C + TSPLIT - 1) / TSPLIT;
  int rbeg = ts * chunk;
  int rend = rbeg + chunk; if (rend > C) rend = C;
  // query key -> 64 VGPRs
  float4 kr[16];
  const float4* kp = (const float4*)(keys + (size_t)q * 64);
  #pragma unroll
  for (int j = 0; j < 16; j++) kr[j] = kp[j];
  float mythr = thr[q];
  for (int r = rbeg; r < rend; r++) {
    const float4* trow = (const float4*)(tk + (size_t)r * 64);  // wave-uniform
    float a0 = 0.f, a1 = 0.f, a2 = 0.f, a3 = 0.f;
    #pragma unroll
    for (int j = 0; j < 16; j++) {
      float4 tv = trow[j];
      a0 += kr[j].x * tv.x; a1 += kr[j].y * tv.y;
      a2 += kr[j].z * tv.z; a3 += kr[j].w * tv.w;
    }
    float dot = (a0 + a1) + (a2 + a3);
    float d2p = tnorm[r] - 2.f * dot;  // d2 minus qn (qn constant per thread)
    if (d2p < mythr) {
      int p = atomicAdd(&cnt[q], 1);
      if (p < cap) {
        candi[(size_t)q * cap + p] = r;
        candd[(size_t)q * cap + p] = d2p;
      }
    }
  }
}

// ---------------- Kernel 4: 50x argmin extraction + weighted sum ----------------
__global__ __launch_bounds__(256) void select_kernel(
    const float* __restrict__ tv, const int* __restrict__ cnt,
    const int* __restrict__ candi, const float* __restrict__ candd,
    const float* __restrict__ qnorm, float* __restrict__ out, int cap) {
  int q = blockIdx.x;
  __shared__ unsigned d2b[MAXCAP];
  __shared__ int cid[MAXCAP];
  __shared__ unsigned long long best;
  __shared__ float acc_w, acc_wv;
  int tid = threadIdx.x;
  int n = cnt[q];
  if (n > cap) n = cap;
  if (n > MAXCAP) n = MAXCAP;
  float qn = qnorm[q];
  for (int i = tid; i < n; i += 256) {
    float d2 = candd[(size_t)q * cap + i] + qn;
    if (d2 < 0.f) d2 = 0.f;                  // keep bits order-preserving
    d2b[i] = __float_as_uint(d2);
    cid[i] = candi[(size_t)q * cap + i];
  }
  if (tid == 0) { acc_w = 0.f; acc_wv = 0.f; }
  __syncthreads();
  int kk = n < K_NEIGH ? n : K_NEIGH;
  for (int it = 0; it < kk; it++) {
    if (tid == 0) best = ~0ULL;
    __syncthreads();
    unsigned long long lm = ~0ULL;
    for (int i = tid; i < n; i += 256) {
      unsigned long long p = ((unsigned long long)d2b[i] << 32) | (unsigned)i;
      if (p < lm) lm = p;
    }
    atomicMin(&best, lm);
    __syncthreads();
    if (tid == 0) {
      unsigned pos = (unsigned)(best & 0xffffffffu);
      float d2 = __uint_as_float((unsigned)(best >> 32));
      float w = 1.f / (d2 + DELTA_SMOOTH);
      acc_w += w;
      acc_wv += w * tv[cid[pos]];
      d2b[pos] = 0xffffffffu;  // extracted -> max key
    }
    __syncthreads();
  }
  if (tid == 0) out[q] = acc_wv / acc_w;
}

extern "C" void kernel_launch(void* const* d_in, const int* in_sizes, int n_in,
                              void* d_out, int out_size, void* d_ws, size_t ws_size,
                              hipStream_t stream) {
  const float* keys = (const float*)d_in[0];   // [B,64]
  const float* tk   = (const float*)d_in[1];   // [C,64]
  const float* tv   = (const float*)d_in[2];   // [C]
  float* out = (float*)d_out;
  int B = in_sizes[0] / 64;   // 1024
  int C = in_sizes[2];        // 500000
  int qtiles = B / 256;       // 4

  // workspace layout
  char* w = (char*)d_ws;
  float* tnorm = (float*)w;  w += (((size_t)C * 4) + 255) / 256 * 256;
  float* thr   = (float*)w;  w += (size_t)B * 4;
  float* qnorm = (float*)w;  w += (size_t)B * 4;
  int*   cnt   = (int*)w;    w += (size_t)B * 4;
  size_t used = (size_t)(w - (char*)d_ws);
  size_t avail = ws_size > used ? ws_size - used : 0;
  int cap = (int)(avail / (8ull * (size_t)B));   // idx + float per candidate
  if (cap > MAXCAP) cap = MAXCAP;
  if (cap < 1) cap = 1;
  int*   candi = (int*)w;
  float* candd = (float*)(w + (size_t)B * cap * 4);

  hipMemsetAsync(cnt, 0, (size_t)B * 4, stream);
  tnorm_kernel<<<(C + 3) / 4, 256, 0, stream>>>(tk, tnorm, C);
  qthresh_kernel<<<B, 256, 0, stream>>>(keys, tk, tnorm, thr, qnorm, C);
  filter_kernel<<<qtiles * TSPLIT, 256, 0, stream>>>(keys, tk, tnorm, thr, cnt,
                                                     candi, candd, C, qtiles, cap);
  select_kernel<<<B, 256, 0, stream>>>(tv, cnt, candi, candd, qnorm, out, cap);
}

// Round 2
// 2284.661 us; speedup vs baseline: 1.4047x; 1.4047x over previous
//
#include <hip/hip_runtime.h>
#include <math.h>

// kNN (B=1024, C=500000, D=64) + inverse-distance weighting, top-50.
// R2: bf16 MFMA radius filter (margin-padded threshold) + exact fp32 rescore
// in select. Pipeline: tnorm -> qthresh (sampled histogram radius) ->
// filter_mfma (candidate append) -> select (rescore + 50x argmin + weights).

#define DELTA_SMOOTH 1e-3f
#define K_NEIGH 50
#define MAXCAP 8192
#define SAMPLE 4096
#define SAMPLE_TARGET 12
#define NBINS 256
#define MARGIN 0.75f         // covers worst-case bf16 dot error (~0.3-0.5)
#define RPB 2048             // table rows per filter block
#define QTILE 256            // queries per filter block (16 waves x 16)

typedef __attribute__((ext_vector_type(8))) short short8;
typedef __attribute__((ext_vector_type(4))) float f32x4;

__device__ __forceinline__ unsigned short f2bf(float f) {
  // round-to-nearest-even fp32 -> bf16 (inputs are finite)
  unsigned u = __float_as_uint(f);
  return (unsigned short)((u + 0x7fffu + ((u >> 16) & 1u)) >> 16);
}

// ---------------- Kernel 1: table row norms (exact fp32) ----------------
__global__ __launch_bounds__(256) void tnorm_kernel(
    const float* __restrict__ tk, float* __restrict__ tnorm, int C) {
  int row = blockIdx.x * 4 + (threadIdx.x >> 6);
  int lane = threadIdx.x & 63;
  if (row >= C) return;
  float v = tk[(size_t)row * 64 + lane];
  float s = v * v;
  #pragma unroll
  for (int off = 32; off > 0; off >>= 1) s += __shfl_down(s, off);
  if (lane == 0) tnorm[row] = s;
}

// ---------------- Kernel 2: per-query radius from sampled histogram ----------------
__global__ __launch_bounds__(256) void qthresh_kernel(
    const float* __restrict__ keys, const float* __restrict__ tk,
    const float* __restrict__ tnorm, float* __restrict__ thr, int C) {
  int q = blockIdx.x;
  __shared__ __align__(16) float kq[64];
  __shared__ unsigned hist[NBINS];
  __shared__ float qn_sh;
  int tid = threadIdx.x;
  if (tid < 64) kq[tid] = keys[(size_t)q * 64 + tid];
  if (tid < NBINS) hist[tid] = 0u;
  __syncthreads();
  if (tid < 64) {
    float v = kq[tid];
    float s = v * v;
    #pragma unroll
    for (int off = 32; off > 0; off >>= 1) s += __shfl_down(s, off);
    if (tid == 0) qn_sh = s;
  }
  __syncthreads();
  float qn = qn_sh;
  const float4* k4 = (const float4*)kq;
  int S = SAMPLE < C ? SAMPLE : C;
  for (int r = tid; r < S; r += 256) {
    const float4* trow = (const float4*)(tk + (size_t)r * 64);
    float a0 = 0.f, a1 = 0.f, a2 = 0.f, a3 = 0.f;
    #pragma unroll
    for (int j = 0; j < 16; j++) {
      float4 tvv = trow[j];
      float4 kv = k4[j];
      a0 += kv.x * tvv.x; a1 += kv.y * tvv.y; a2 += kv.z * tvv.z; a3 += kv.w * tvv.w;
    }
    float dot = (a0 + a1) + (a2 + a3);
    float d2 = qn + tnorm[r] - 2.f * dot;
    int b = (int)d2;
    b = b < 0 ? 0 : (b > NBINS - 1 ? NBINS - 1 : b);
    atomicAdd(&hist[b], 1u);
  }
  __syncthreads();
  if (tid == 0) {
    unsigned cum = 0;
    int bstar = NBINS - 1;
    for (int b = 0; b < NBINS; b++) {
      cum += hist[b];
      if (cum >= SAMPLE_TARGET) { bstar = b; break; }
    }
    // filter compares (tn - 2*dot_bf16) < thr  <=>  d2 < bstar+1+MARGIN
    thr[q] = (float)(bstar + 1) + MARGIN - qn;
  }
}

// ---------------- Kernel 3: bf16 MFMA radius filter ----------------
// Block: 1024 thr = 16 waves; wave w owns 16 queries; block covers 256 queries
// x RPB table rows. Per iter: 32 rows staged fp32->bf16 into swizzled LDS,
// each wave does 2 (16x16) N-tiles x 2 K-steps of mfma_f32_16x16x32_bf16.
__global__ __launch_bounds__(1024) void filter_mfma_kernel(
    const float* __restrict__ keys, const float* __restrict__ tk,
    const float* __restrict__ tnorm, const float* __restrict__ thr,
    int* __restrict__ cnt, int* __restrict__ candi, int C, int qtiles, int cap) {
  __shared__ float tnorm_lds[RPB];
  __shared__ float thr_lds[QTILE];
  __shared__ __align__(16) unsigned char bstage[32 * 128];  // 32 rows x 64 bf16

  int tid = threadIdx.x;
  int qt = blockIdx.x % qtiles;
  int chunk = blockIdx.x / qtiles;
  int qbase = qt * QTILE;
  int rstart = chunk * RPB;

  for (int i = tid; i < RPB; i += 1024) {
    int r = rstart + i; if (r > C - 1) r = C - 1;
    tnorm_lds[i] = tnorm[r];
  }
  if (tid < QTILE) thr_lds[tid] = thr[qbase + tid];

  int lane = tid & 63;
  int wq = tid >> 6;       // wave 0..15
  int l15 = lane & 15;
  int quad = lane >> 4;    // 0..3

  // A fragments: A[m=lane&15][k = s*32 + quad*8 + j]  (verified layout)
  short8 afrag[2];
  {
    const float* kp = keys + (size_t)(qbase + wq * 16 + l15) * 64 + quad * 8;
    #pragma unroll
    for (int s = 0; s < 2; ++s) {
      float4 x = *(const float4*)(kp + s * 32);
      float4 y = *(const float4*)(kp + s * 32 + 4);
      short8 a;
      a[0] = (short)f2bf(x.x); a[1] = (short)f2bf(x.y);
      a[2] = (short)f2bf(x.z); a[3] = (short)f2bf(x.w);
      a[4] = (short)f2bf(y.x); a[5] = (short)f2bf(y.y);
      a[6] = (short)f2bf(y.z); a[7] = (short)f2bf(y.w);
      afrag[s] = a;
    }
  }
  __syncthreads();

  // wave-max threshold (precheck); exact thr re-checked in slow path
  float thw = thr_lds[wq * 16 + l15];
  #pragma unroll
  for (int off = 1; off < 16; off <<= 1) thw = fmaxf(thw, __shfl_xor(thw, off));

  // staging address: row srow, bf16 pair at k2; chunk XOR-swizzle vs row
  int srow = tid >> 5;             // 0..31
  int k2 = (tid & 31) * 2;         // 0..62
  int sc = k2 >> 3;
  unsigned sbyte = (unsigned)(srow * 128 + ((sc ^ (srow & 7)) << 4) + (k2 & 7) * 2);

  const int ITERS = RPB / 32;
  int r0 = rstart + srow; if (r0 > C - 1) r0 = C - 1;
  float2 pre = *(const float2*)(tk + (size_t)r0 * 64 + k2);

  f32x4 zero4 = {0.f, 0.f, 0.f, 0.f};

  for (int it = 0; it < ITERS; ++it) {
    unsigned u0 = (unsigned)f2bf(pre.x) | ((unsigned)f2bf(pre.y) << 16);
    *(unsigned*)(bstage + sbyte) = u0;
    __syncthreads();
    if (it + 1 < ITERS) {  // prefetch next tile while computing this one
      int rn = rstart + (it + 1) * 32 + srow; if (rn > C - 1) rn = C - 1;
      pre = *(const float2*)(tk + (size_t)rn * 64 + k2);
    }
    // B fragments: B[k = s*32 + quad*8 + j][n = t*16 + lane&15]
    short8 b[2][2];
    #pragma unroll
    for (int t = 0; t < 2; ++t) {
      int nloc = t * 16 + l15;
      #pragma unroll
      for (int s = 0; s < 2; ++s) {
        int c = s * 4 + quad;
        unsigned addr = (unsigned)(nloc * 128 + ((c ^ (nloc & 7)) << 4));
        b[t][s] = *(const short8*)(bstage + addr);
      }
    }
    f32x4 acc0 = __builtin_amdgcn_mfma_f32_16x16x32_bf16(afrag[0], b[0][0], zero4, 0, 0, 0);
    acc0 = __builtin_amdgcn_mfma_f32_16x16x32_bf16(afrag[1], b[0][1], acc0, 0, 0, 0);
    f32x4 acc1 = __builtin_amdgcn_mfma_f32_16x16x32_bf16(afrag[0], b[1][0], zero4, 0, 0, 0);
    acc1 = __builtin_amdgcn_mfma_f32_16x16x32_bf16(afrag[1], b[1][1], acc1, 0, 0, 0);

    int rowbase = it * 32;
    #pragma unroll
    for (int t = 0; t < 2; ++t) {
      f32x4 acc = (t == 0) ? acc0 : acc1;
      int n = rstart + rowbase + t * 16 + l15;
      float tn = tnorm_lds[rowbase + t * 16 + l15];
      #pragma unroll
      for (int r = 0; r < 4; ++r) {
        // C/D layout: col(n)=lane&15, row(m)=quad*4+r  (verified m89/m91)
        float d2p = fmaf(-2.f, acc[r], tn);
        if (d2p < thw) {
          int m = quad * 4 + r;
          float te = thr_lds[wq * 16 + m];
          if (d2p < te && n < C) {
            int qq = qbase + wq * 16 + m;
            int p = atomicAdd(&cnt[qq], 1);
            if (p < cap) candi[(size_t)qq * cap + p] = n;
          }
        }
      }
    }
    __syncthreads();
  }
}

// ---------------- Kernel 4: exact fp32 rescore + 50x argmin + weighted sum ----------------
__global__ __launch_bounds__(256) void select_kernel(
    const float* __restrict__ keys, const float* __restrict__ tk,
    const float* __restrict__ tv, const int* __restrict__ cnt,
    const int* __restrict__ candi, float* __restrict__ out, int cap, int C) {
  int q = blockIdx.x;
  __shared__ unsigned d2b[MAXCAP];
  __shared__ int cid[MAXCAP];
  __shared__ unsigned long long wmin[4];
  __shared__ float win_d2[K_NEIGH];
  __shared__ int win_idx[K_NEIGH];
  int tid = threadIdx.x;
  int lane = tid & 63;
  int wid = tid >> 6;
  int n = cnt[q];
  if (n > cap) n = cap;
  if (n > MAXCAP) n = MAXCAP;
  float kq = keys[(size_t)q * 64 + lane];
  const int* ci = candi + (size_t)q * cap;
  // phase 1: exact rescore, wave per candidate, 4x unrolled for MLP
  for (int i0 = wid * 4; i0 < n; i0 += 16) {
    int m = n - i0; if (m > 4) m = 4;
    int idx[4]; float t[4];
    for (int u = 0; u < m; ++u) idx[u] = ci[i0 + u];
    for (int u = 0; u < m; ++u) t[u] = tk[(size_t)idx[u] * 64 + lane];
    for (int u = 0; u < m; ++u) {
      float d = t[u] - kq;
      float s = d * d;
      #pragma unroll
      for (int off = 1; off < 64; off <<= 1) s += __shfl_xor(s, off);
      if (lane == 0) { d2b[i0 + u] = __float_as_uint(s); cid[i0 + u] = idx[u]; }
    }
  }
  __syncthreads();
  // phase 2: K extractions via shuffle-min on (d2 bits << 32 | pos)
  int kk = n < K_NEIGH ? n : K_NEIGH;
  for (int it = 0; it < kk; ++it) {
    unsigned long long lm = ~0ULL;
    for (int i = tid; i < n; i += 256) {
      unsigned long long p = ((unsigned long long)d2b[i] << 32) | (unsigned)i;
      if (p < lm) lm = p;
    }
    #pragma unroll
    for (int off = 1; off < 64; off <<= 1) {
      unsigned long long o = __shfl_xor(lm, off);
      if (o < lm) lm = o;
    }
    if (lane == 0) wmin[wid] = lm;
    __syncthreads();
    if (tid == 0) {
      unsigned long long bb = wmin[0];
      for (int w2 = 1; w2 < 4; ++w2) if (wmin[w2] < bb) bb = wmin[w2];
      unsigned pos = (unsigned)(bb & 0xffffffffu);
      win_d2[it] = __uint_as_float((unsigned)(bb >> 32));
      win_idx[it] = cid[pos];
      d2b[pos] = 0xffffffffu;
    }
    __syncthreads();
  }
  // phase 3: gather 50 values in parallel, wave-reduce weighted sum
  if (tid < 64) {
    float wgt = 0.f, wv = 0.f;
    if (tid < kk) {
      float d2 = win_d2[tid];
      wgt = 1.f / (d2 + DELTA_SMOOTH);
      wv = wgt * tv[win_idx[tid]];
    }
    #pragma unroll
    for (int off = 1; off < 64; off <<= 1) {
      wgt += __shfl_xor(wgt, off);
      wv += __shfl_xor(wv, off);
    }
    if (tid == 0) out[q] = wv / wgt;
  }
}

extern "C" void kernel_launch(void* const* d_in, const int* in_sizes, int n_in,
                              void* d_out, int out_size, void* d_ws, size_t ws_size,
                              hipStream_t stream) {
  const float* keys = (const float*)d_in[0];   // [B,64]
  const float* tk   = (const float*)d_in[1];   // [C,64]
  const float* tv   = (const float*)d_in[2];   // [C]
  float* out = (float*)d_out;
  int B = in_sizes[0] / 64;   // 1024
  int C = in_sizes[2];        // 500000
  int qtiles = B / QTILE;     // 4

  char* w = (char*)d_ws;
  float* tnorm = (float*)w;  w += (((size_t)C * 4) + 255) / 256 * 256;
  float* thr   = (float*)w;  w += (size_t)B * 4;
  int*   cnt   = (int*)w;    w += (size_t)B * 4;
  size_t used = (size_t)(w - (char*)d_ws);
  size_t avail = ws_size > used ? ws_size - used : 0;
  int cap = (int)(avail / (4ull * (size_t)B));   // idx per candidate
  if (cap > MAXCAP) cap = MAXCAP;
  if (cap < 1) cap = 1;
  int* candi = (int*)w;

  hipMemsetAsync(cnt, 0, (size_t)B * 4, stream);
  tnorm_kernel<<<(C + 3) / 4, 256, 0, stream>>>(tk, tnorm, C);
  qthresh_kernel<<<B, 256, 0, stream>>>(keys, tk, tnorm, thr, C);
  int nchunks = (C + RPB - 1) / RPB;
  filter_mfma_kernel<<<nchunks * qtiles, 1024, 0, stream>>>(
      keys, tk, tnorm, thr, cnt, candi, C, qtiles, cap);
  select_kernel<<<B, 256, 0, stream>>>(keys, tk, tv, cnt, candi, out, cap, C);
}

// Round 3
// 594.010 us; speedup vs baseline: 5.4028x; 3.8462x over previous
//
#include <hip/hip_runtime.h>
#include <math.h>

// kNN (B=1024, C=500000, D=64) + inverse-distance weighting, top-50.
// R3: filter stores packed (d2q13<<19|idx) via LDS staging (no global atomics
// in hot loop); select pre-selects ~150 by approx d2 then exact-rescores.
// Pipeline: tnorm -> qthresh -> filter_mfma -> select.

#define DELTA_SMOOTH 1e-3f
#define K_NEIGH 50
#define MAXCAP 8192
#define SAMPLE 2048
#define SAMPLE_TARGET 6
#define NBINS 256
#define MARGIN 0.75f       // bf16 dot worst-case error margin (d2 units)
#define MARGIN_Q 26        // select margin: 2*(0.75+1/16)*16 quanta
#define RPB 1024           // table rows per filter block
#define SDEPTH 8           // LDS staging slots per (block,query); lambda=3
#define LW 1024            // select rescore list size
#define NQ 1024            // queries (fixed by problem)

typedef __attribute__((ext_vector_type(8))) short short8;
typedef __attribute__((ext_vector_type(4))) float f32x4;

__device__ __forceinline__ unsigned short f2bf(float f) {
  unsigned u = __float_as_uint(f);
  return (unsigned short)((u + 0x7fffu + ((u >> 16) & 1u)) >> 16);
}

// ---------------- Kernel 1: table row norms (exact fp32) ----------------
__global__ __launch_bounds__(256) void tnorm_kernel(
    const float* __restrict__ tk, float* __restrict__ tnorm, int C) {
  int row = blockIdx.x * 4 + (threadIdx.x >> 6);
  int lane = threadIdx.x & 63;
  if (row >= C) return;
  float v = tk[(size_t)row * 64 + lane];
  float s = v * v;
  #pragma unroll
  for (int off = 32; off > 0; off >>= 1) s += __shfl_down(s, off);
  if (lane == 0) tnorm[row] = s;
}

// ---------------- Kernel 2: per-query radius from sampled histogram ----------------
// 4 lanes cooperate per row: fully coalesced float4 loads.
__global__ __launch_bounds__(256) void qthresh_kernel(
    const float* __restrict__ keys, const float* __restrict__ tk,
    const float* __restrict__ tnorm, float* __restrict__ thr,
    float* __restrict__ qnorm, int C) {
  int q = blockIdx.x;
  __shared__ __align__(16) float kq[64];
  __shared__ unsigned hist[NBINS];
  __shared__ float qn_sh;
  __shared__ unsigned wsum[4];
  __shared__ int bstar_sh;
  int tid = threadIdx.x;
  int lane = tid & 63;
  int wid = tid >> 6;
  if (tid < 64) kq[tid] = keys[(size_t)q * 64 + tid];
  hist[tid] = 0u;
  if (tid == 0) bstar_sh = NBINS - 1;
  __syncthreads();
  if (tid < 64) {
    float v = kq[tid];
    float s = v * v;
    #pragma unroll
    for (int off = 32; off > 0; off >>= 1) s += __shfl_down(s, off);
    if (tid == 0) qn_sh = s;
  }
  __syncthreads();
  float qn = qn_sh;
  int kc = lane & 3;
  const float4* kq4 = (const float4*)kq;
  float4 kf[4];
  #pragma unroll
  for (int j = 0; j < 4; ++j) kf[j] = kq4[kc * 4 + j];
  int S = SAMPLE < C ? SAMPLE : C;
  // wave covers rows [wid*512, wid*512+512), 16 rows per step
  for (int r = wid * (S >> 2) + (lane >> 2); r < (wid + 1) * (S >> 2); r += 16) {
    const float4* trow = (const float4*)(tk + (size_t)r * 64 + kc * 16);
    float a0 = 0.f, a1 = 0.f;
    #pragma unroll
    for (int j = 0; j < 4; ++j) {
      float4 tvv = trow[j];
      float4 kv = kf[j];
      a0 += kv.x * tvv.x + kv.y * tvv.y;
      a1 += kv.z * tvv.z + kv.w * tvv.w;
    }
    float s = a0 + a1;
    s += __shfl_xor(s, 1);
    s += __shfl_xor(s, 2);
    if (kc == 0) {
      float d2 = qn + tnorm[r] - 2.f * s;
      int b = (int)d2;
      b = b < 0 ? 0 : (b > NBINS - 1 ? NBINS - 1 : b);
      atomicAdd(&hist[b], 1u);
    }
  }
  __syncthreads();
  // parallel inclusive prefix over 256 bins (one per thread)
  unsigned h = hist[tid];
  unsigned p = h;
  #pragma unroll
  for (int off = 1; off < 64; off <<= 1) {
    unsigned v = __shfl_up(p, off);
    if (lane >= off) p += v;
  }
  if (lane == 63) wsum[wid] = p;
  __syncthreads();
  unsigned add = 0;
  for (int w2 = 0; w2 < wid; ++w2) add += wsum[w2];
  p += add;
  if (p >= (unsigned)SAMPLE_TARGET && p - h < (unsigned)SAMPLE_TARGET) bstar_sh = tid;
  __syncthreads();
  if (tid == 0) {
    thr[q] = (float)(bstar_sh + 1) + MARGIN - qn;
    qnorm[q] = qn;
  }
}

// ---------------- Kernel 3: bf16 MFMA radius filter ----------------
// 1 block per 1024-row chunk; block covers ALL 1024 queries (table read once).
// 16 waves; wave owns 64 queries via 4 m-tiles of 16x16x32 MFMA (verified
// layouts from R2). Hits -> LDS staging buffer, one global atomic per
// (block,query) at flush. Payload: (d2q13 << 19) | row_idx  (C < 2^19).
__global__ __launch_bounds__(1024, 4) void filter_mfma_kernel(
    const float* __restrict__ keys, const float* __restrict__ tk,
    const float* __restrict__ tnorm, const float* __restrict__ thr,
    const float* __restrict__ qnorm, int* __restrict__ cnt,
    unsigned* __restrict__ candi, int C, int cap) {
  __shared__ float tnorm_lds[RPB];                    // 4 KB
  __shared__ float thr_lds[NQ];                       // 4 KB
  __shared__ float qn_lds[NQ];                        // 4 KB
  __shared__ unsigned scnt[NQ];                       // 4 KB
  __shared__ unsigned sbuf[NQ * SDEPTH];              // 32 KB
  __shared__ __align__(16) unsigned char bstage[32 * 128];  // 4 KB

  int tid = threadIdx.x;
  int rstart = blockIdx.x * RPB;
  {
    int r = rstart + tid; if (r > C - 1) r = C - 1;
    tnorm_lds[tid] = tnorm[r];
    thr_lds[tid] = thr[tid];
    qn_lds[tid] = qnorm[tid];
    scnt[tid] = 0u;
  }
  int lane = tid & 63;
  int wq = tid >> 6;
  int l15 = lane & 15;
  int quad = lane >> 4;

  // A fragments: 4 m-tiles x 2 K-halves; A[m=l15][k=s*32+quad*8+j]
  short8 afrag[4][2];
  #pragma unroll
  for (int mt = 0; mt < 4; ++mt) {
    const float* kp = keys + (size_t)(wq * 64 + mt * 16 + l15) * 64 + quad * 8;
    #pragma unroll
    for (int s = 0; s < 2; ++s) {
      float4 x = *(const float4*)(kp + s * 32);
      float4 y = *(const float4*)(kp + s * 32 + 4);
      short8 a;
      a[0] = (short)f2bf(x.x); a[1] = (short)f2bf(x.y);
      a[2] = (short)f2bf(x.z); a[3] = (short)f2bf(x.w);
      a[4] = (short)f2bf(y.x); a[5] = (short)f2bf(y.y);
      a[6] = (short)f2bf(y.z); a[7] = (short)f2bf(y.w);
      afrag[mt][s] = a;
    }
  }
  __syncthreads();

  // wave-max threshold precheck (exact thr re-checked in masked body)
  float thw = thr_lds[wq * 64 + lane];
  #pragma unroll
  for (int off = 1; off < 64; off <<= 1) thw = fmaxf(thw, __shfl_xor(thw, off));

  int srow = tid >> 5;            // 0..31
  int k2 = (tid & 31) * 2;        // 0..62
  int sc = k2 >> 3;
  unsigned sbyte = (unsigned)(srow * 128 + ((sc ^ (srow & 7)) << 4) + (k2 & 7) * 2);

  const int ITERS = RPB / 32;
  int r0 = rstart + srow; if (r0 > C - 1) r0 = C - 1;
  float2 pre = *(const float2*)(tk + (size_t)r0 * 64 + k2);

  f32x4 zero4 = {0.f, 0.f, 0.f, 0.f};

  for (int it = 0; it < ITERS; ++it) {
    *(unsigned*)(bstage + sbyte) =
        (unsigned)f2bf(pre.x) | ((unsigned)f2bf(pre.y) << 16);
    __syncthreads();
    if (it + 1 < ITERS) {
      int rn = rstart + (it + 1) * 32 + srow; if (rn > C - 1) rn = C - 1;
      pre = *(const float2*)(tk + (size_t)rn * 64 + k2);
    }
    // B fragments (shared across m-tiles): B[k=s*32+quad*8+j][n=t*16+l15]
    short8 b[2][2];
    #pragma unroll
    for (int t = 0; t < 2; ++t) {
      int nloc = t * 16 + l15;
      #pragma unroll
      for (int s = 0; s < 2; ++s) {
        int c = s * 4 + quad;
        unsigned addr = (unsigned)(nloc * 128 + ((c ^ (nloc & 7)) << 4));
        b[t][s] = *(const short8*)(bstage + addr);
      }
    }
    f32x4 acc[4][2];
    #pragma unroll
    for (int mt = 0; mt < 4; ++mt) {
      #pragma unroll
      for (int t = 0; t < 2; ++t) {
        f32x4 a0 = __builtin_amdgcn_mfma_f32_16x16x32_bf16(afrag[mt][0], b[t][0], zero4, 0, 0, 0);
        acc[mt][t] = __builtin_amdgcn_mfma_f32_16x16x32_bf16(afrag[mt][1], b[t][1], a0, 0, 0, 0);
      }
    }
    int rowb = it * 32;
    float tn0 = tnorm_lds[rowb + l15];
    float tn1 = tnorm_lds[rowb + 16 + l15];
    int n0 = rstart + rowb + l15;
    #pragma unroll
    for (int mt = 0; mt < 4; ++mt) {
      #pragma unroll
      for (int t = 0; t < 2; ++t) {
        float tn = t ? tn1 : tn0;
        int n = n0 + t * 16;
        #pragma unroll
        for (int r = 0; r < 4; ++r) {
          // C/D layout: col(n)=lane&15, row(m)=quad*4+r
          float d2p = fmaf(-2.f, acc[mt][t][r], tn);
          if (d2p < thw) {
            int ql = wq * 64 + mt * 16 + quad * 4 + r;
            if (d2p < thr_lds[ql] && n < C) {
              float d2f = d2p + qn_lds[ql];
              int d2q = (int)(d2f * 16.f);
              d2q = d2q < 0 ? 0 : (d2q > 8191 ? 8191 : d2q);
              unsigned v = ((unsigned)d2q << 19) | (unsigned)n;
              unsigned p = atomicAdd(&scnt[ql], 1u);
              if (p < SDEPTH) {
                sbuf[ql * SDEPTH + p] = v;
              } else {  // rare overflow -> direct global append
                int g = atomicAdd(&cnt[ql], 1);
                if (g < cap) candi[(size_t)ql * cap + g] = v;
              }
            }
          }
        }
      }
    }
    __syncthreads();
  }
  // flush: one global atomic per (block, query)
  int m = (int)scnt[tid];
  if (m > SDEPTH) m = SDEPTH;
  if (m > 0) {
    int base = atomicAdd(&cnt[tid], m);
    for (int j = 0; j < m; ++j) {
      int g = base + j;
      if (g < cap) candi[(size_t)tid * cap + g] = sbuf[tid * SDEPTH + j];
    }
  }
}

// ---------------- Kernel 4: approx pre-select + exact rescore + top-50 ----------------
__global__ __launch_bounds__(256) void select_kernel(
    const float* __restrict__ keys, const float* __restrict__ tk,
    const float* __restrict__ tv, const int* __restrict__ cnt,
    const unsigned* __restrict__ candi, float* __restrict__ out,
    int cap, int C) {
  int q = blockIdx.x;
  __shared__ unsigned hist[NBINS];
  __shared__ unsigned wsum[4];
  __shared__ int bstar_sh;
  __shared__ unsigned Tsh;
  __shared__ int lidx[LW];
  __shared__ unsigned ed2[LW];
  __shared__ int m_sh;
  __shared__ unsigned long long wmin[4];
  __shared__ float win_d2[K_NEIGH];
  __shared__ int win_idx[K_NEIGH];
  int tid = threadIdx.x;
  int lane = tid & 63;
  int wid = tid >> 6;
  int n = cnt[q];
  if (n > cap) n = cap;
  hist[tid] = 0u;
  if (tid == 0) { bstar_sh = NBINS - 1; m_sh = 0; }
  __syncthreads();
  const unsigned* cv = candi + (size_t)q * cap;
  // phase A: histogram of approx d2 (v>>24 = d2q>>5, bin width 2.0 d2)
  for (int i = tid; i < n; i += 256) atomicAdd(&hist[cv[i] >> 24], 1u);
  __syncthreads();
  unsigned h = hist[tid];
  unsigned p = h;
  #pragma unroll
  for (int off = 1; off < 64; off <<= 1) {
    unsigned v = __shfl_up(p, off);
    if (lane >= off) p += v;
  }
  if (lane == 63) wsum[wid] = p;
  __syncthreads();
  unsigned add = 0;
  for (int w2 = 0; w2 < wid; ++w2) add += wsum[w2];
  p += add;
  if (p >= (unsigned)K_NEIGH && p - h < (unsigned)K_NEIGH) bstar_sh = tid;
  __syncthreads();
  if (tid == 0) {
    unsigned long long T64 =
        (((unsigned long long)(bstar_sh + 1)) << 24) + ((unsigned long long)MARGIN_Q << 19);
    Tsh = T64 > 0xffffffffull ? 0xffffffffu : (unsigned)T64;
  }
  __syncthreads();
  unsigned T = Tsh;
  // phase B: compact candidates within margin of the 50th bin
  for (int i = tid; i < n; i += 256) {
    unsigned v = cv[i];
    if (v < T) {
      int p2 = atomicAdd(&m_sh, 1);
      if (p2 < LW) lidx[p2] = (int)(v & 0x7ffffu);
    }
  }
  __syncthreads();
  int m = m_sh; if (m > LW) m = LW;
  // phase C: exact fp32 rescore (wave per candidate, 4x ILP)
  float kqv = keys[(size_t)q * 64 + lane];
  for (int i0 = wid * 4; i0 < m; i0 += 16) {
    int mm = m - i0; if (mm > 4) mm = 4;
    int idx[4]; float t[4];
    for (int u = 0; u < mm; ++u) idx[u] = lidx[i0 + u];
    for (int u = 0; u < mm; ++u) t[u] = tk[(size_t)idx[u] * 64 + lane];
    for (int u = 0; u < mm; ++u) {
      float d = t[u] - kqv;
      float s = d * d;
      #pragma unroll
      for (int off = 1; off < 64; off <<= 1) s += __shfl_xor(s, off);
      if (lane == 0) ed2[i0 + u] = __float_as_uint(s);
    }
  }
  __syncthreads();
  // phase D: 50 extractions over ~m elements
  int kk = m < K_NEIGH ? m : K_NEIGH;
  for (int it = 0; it < kk; ++it) {
    unsigned long long lm = ~0ULL;
    for (int i = tid; i < m; i += 256) {
      unsigned long long pp = ((unsigned long long)ed2[i] << 32) | (unsigned)i;
      if (pp < lm) lm = pp;
    }
    #pragma unroll
    for (int off = 1; off < 64; off <<= 1) {
      unsigned long long o = __shfl_xor(lm, off);
      if (o < lm) lm = o;
    }
    if (lane == 0) wmin[wid] = lm;
    __syncthreads();
    if (tid == 0) {
      unsigned long long bb = wmin[0];
      for (int w2 = 1; w2 < 4; ++w2) if (wmin[w2] < bb) bb = wmin[w2];
      unsigned pos = (unsigned)(bb & 0xffffffffu);
      win_d2[it] = __uint_as_float((unsigned)(bb >> 32));
      win_idx[it] = lidx[pos];
      ed2[pos] = 0xffffffffu;
    }
    __syncthreads();
  }
  // phase E: weighted sum
  if (tid < 64) {
    float wgt = 0.f, wv = 0.f;
    if (tid < kk) {
      float d2 = win_d2[tid];
      wgt = 1.f / (d2 + DELTA_SMOOTH);
      wv = wgt * tv[win_idx[tid]];
    }
    #pragma unroll
    for (int off = 1; off < 64; off <<= 1) {
      wgt += __shfl_xor(wgt, off);
      wv += __shfl_xor(wv, off);
    }
    if (tid == 0) out[q] = wv / wgt;
  }
}

extern "C" void kernel_launch(void* const* d_in, const int* in_sizes, int n_in,
                              void* d_out, int out_size, void* d_ws, size_t ws_size,
                              hipStream_t stream) {
  const float* keys = (const float*)d_in[0];   // [B,64]
  const float* tk   = (const float*)d_in[1];   // [C,64]
  const float* tv   = (const float*)d_in[2];   // [C]
  float* out = (float*)d_out;
  int B = in_sizes[0] / 64;   // 1024
  int C = in_sizes[2];        // 500000 (< 2^19 for packing)

  char* w = (char*)d_ws;
  float* tnorm = (float*)w;  w += (((size_t)C * 4) + 255) / 256 * 256;
  float* thr   = (float*)w;  w += (size_t)B * 4;
  float* qn    = (float*)w;  w += (size_t)B * 4;
  int*   cnt   = (int*)w;    w += (size_t)B * 4;
  size_t used = (size_t)(w - (char*)d_ws);
  size_t avail = ws_size > used ? ws_size - used : 0;
  int cap = (int)(avail / (4ull * (size_t)B));
  if (cap > MAXCAP) cap = MAXCAP;
  if (cap < 1) cap = 1;
  unsigned* candi = (unsigned*)w;

  hipMemsetAsync(cnt, 0, (size_t)B * 4, stream);
  tnorm_kernel<<<(C + 3) / 4, 256, 0, stream>>>(tk, tnorm, C);
  qthresh_kernel<<<B, 256, 0, stream>>>(keys, tk, tnorm, thr, qn, C);
  int nchunks = (C + RPB - 1) / RPB;
  filter_mfma_kernel<<<nchunks, 1024, 0, stream>>>(keys, tk, tnorm, thr, qn,
                                                   cnt, candi, C, cap);
  select_kernel<<<B, 256, 0, stream>>>(keys, tk, tv, cnt, candi, out, cap, C);
}